// Round 8
// baseline (1409.230 us; speedup 1.0000x reference)
//
#include <hip/hip_runtime.h>
#include <hip/hip_bf16.h>

// ---------------- constants ----------------
#define BB 32
#define TT 128
#define DD 512
#define NW 2000
#define NCC 200
#define SS 8
#define LL 4
#define HH 8
#define FF 2048
#define HD 64

typedef unsigned short ushort_t;
typedef __attribute__((ext_vector_type(8))) short bhalf8;
typedef __attribute__((ext_vector_type(4))) float floatx4;

__device__ inline ushort_t f2b(float x) {
    union { float f; unsigned int u; } v; v.f = x;
    unsigned int r = (v.u + 0x7FFFu + ((v.u >> 16) & 1u)) >> 16;
    return (ushort_t)r;
}
__device__ inline float b2f(ushort_t u) {
    union { unsigned int u; float f; } v; v.u = ((unsigned int)u) << 16;
    return v.f;
}
__device__ inline void gld16(const ushort_t* g, ushort_t* l) {
    __builtin_amdgcn_global_load_lds(
        (const __attribute__((address_space(1))) void*)g,
        (__attribute__((address_space(3))) void*)l, 16, 0, 0);
}

// ================= bf16 MFMA GEMM (single-buffer 32KiB, m97 structure) ======
// C[M,N] = act( alpha * sum_tap A[M,K] @ B[N,K]^T + bias )
// batch z: zb=z/batchH, zh=z%batchH; offsets sA1*zb+sA2*zh etc (elements).
// Single-buffered LDS (32 KiB) -> 4-5 blocks/CU; cross-block wave overlap
// hides the vmcnt-drain barrier stall (m97/m99: explicit dbuf adds nothing).
template<int ACT, int OUTBF>
__global__ __launch_bounds__(256) void bgemm_k(
    const ushort_t* __restrict__ A, int lda, long sA1, long sA2,
    const ushort_t* __restrict__ B, int ldb, long sB1, long sB2,
    void* __restrict__ Cv, int ldc, long sC1, long sC2,
    const float* __restrict__ bias,
    int M, int N, int K, float alpha, int batchH,
    int taps, long tapA, long tapB, const ushort_t* __restrict__ zbuf)
{
    __shared__ __align__(16) ushort_t sm[2][128 * 64];  // 32 KiB: [0]=A, [1]=B
    int z = blockIdx.z;
    int zb = z / batchH, zh = z % batchH;
    A += (long)zb * sA1 + (long)zh * sA2;
    B += (long)zb * sB1 + (long)zh * sB2;
    long cOff = (long)zb * sC1 + (long)zh * sC2;
    int m0 = blockIdx.y * 128, n0 = blockIdx.x * 128;
    int tid = threadIdx.x;
    int wid = tid >> 6, lane = tid & 63;
    int wr = wid >> 1, wc = wid & 1;
    int lr = lane & 15, lg = lane >> 4;

    int kSteps = (K + 63) >> 6;
    int nt = taps * kSteps;

    int rsub = lane >> 3;
    int ssub = lane & 7;
    int scol = ((ssub ^ rsub) << 3);      // pre-swizzled logical col (bf16)
    bool aok[4], bok[4];
    const ushort_t* aptr[4];
    const ushort_t* bptr[4];
    #pragma unroll
    for (int i = 0; i < 4; i++) {
        int row = (wid << 5) + (i << 3) + rsub;
        aok[i] = (m0 + row) < M;
        bok[i] = (n0 + row) < N;
        aptr[i] = A + (long)(m0 + row) * lda + scol;
        bptr[i] = B + (long)(n0 + row) * ldb + scol;
    }

    floatx4 acc[4][4];
    #pragma unroll
    for (int i = 0; i < 4; i++)
        #pragma unroll
        for (int j = 0; j < 4; j++)
            acc[i][j] = (floatx4){0.f, 0.f, 0.f, 0.f};

    int tap_n = 0, k0_n = 0;
    for (int t = 0; t < nt; t++) {
        // stage tile t (async global->LDS)
        {
            bool kOk = (k0_n + scol) < K;
            #pragma unroll
            for (int i = 0; i < 4; i++) {
                const ushort_t* as =
                    (kOk && aok[i]) ? (aptr[i] + (long)tap_n * tapA + k0_n) : zbuf;
                const ushort_t* bs =
                    (kOk && bok[i]) ? (bptr[i] + (long)tap_n * tapB + k0_n) : zbuf;
                int lb = ((wid << 5) + (i << 3)) << 6;
                gld16(as, &sm[0][lb]);
                gld16(bs, &sm[1][lb]);
            }
        }
        __syncthreads();   // drains vmcnt: tile resident
        const char* Ab = (const char*)&sm[0][0];
        const char* Bbs = (const char*)&sm[1][0];
        #pragma unroll
        for (int kk = 0; kk < 2; kk++) {
            bhalf8 a_[4], b_[4];
            #pragma unroll
            for (int i = 0; i < 4; i++) {
                int r = wr * 64 + i * 16 + lr;
                int off = (r << 7) + (((kk << 6) + (lg << 4)) ^ ((r & 7) << 4));
                a_[i] = *(const bhalf8*)(Ab + off);
            }
            #pragma unroll
            for (int j = 0; j < 4; j++) {
                int r = wc * 64 + j * 16 + lr;
                int off = (r << 7) + (((kk << 6) + (lg << 4)) ^ ((r & 7) << 4));
                b_[j] = *(const bhalf8*)(Bbs + off);
            }
            #pragma unroll
            for (int i = 0; i < 4; i++)
                #pragma unroll
                for (int j = 0; j < 4; j++)
                    acc[i][j] = __builtin_amdgcn_mfma_f32_16x16x32_bf16(
                        a_[i], b_[j], acc[i][j], 0, 0, 0);
        }
        __syncthreads();   // all waves done reading before next stage
        k0_n += 64;
        if (k0_n >= K) { k0_n = 0; ++tap_n; }
    }

    // epilogue: C/D layout col=lane&15, row=(lane>>4)*4+reg
    #pragma unroll
    for (int i = 0; i < 4; i++) {
        int gm_base = m0 + wr * 64 + i * 16 + lg * 4;
        #pragma unroll
        for (int j = 0; j < 4; j++) {
            int gn = n0 + wc * 64 + j * 16 + lr;
            if (gn >= N) continue;
            float bv = bias ? bias[gn] : 0.f;
            #pragma unroll
            for (int r = 0; r < 4; r++) {
                int gm = gm_base + r;
                if (gm >= M) continue;
                float v = acc[i][j][r] * alpha + bv;
                if (ACT == 1) v = fmaxf(v, 0.f);
                long idx = cOff + (long)gm * ldc + gn;
                if (OUTBF) ((ushort_t*)Cv)[idx] = f2b(v);
                else       ((float*)Cv)[idx] = v;
            }
        }
    }
}

static void launch_bgemm(int act, int outbf,
                         const ushort_t* A, int lda, long sA1, long sA2,
                         const ushort_t* B, int ldb, long sB1, long sB2,
                         void* C, int ldc, long sC1, long sC2,
                         const float* bias, int M, int N, int K, float alpha,
                         int batchH, int Z, int taps, long tapA, long tapB,
                         const ushort_t* zbuf, hipStream_t st) {
    dim3 grid((N + 127) / 128, (M + 127) / 128, Z), blk(256);
#define BG(A_, O_) bgemm_k<A_, O_><<<grid, blk, 0, st>>>(A, lda, sA1, sA2, B, ldb, sB1, sB2, C, ldc, sC1, sC2, bias, M, N, K, alpha, batchH, taps, tapA, tapB, zbuf)
    if (act) { if (outbf) BG(1, 1); else BG(1, 0); }
    else     { if (outbf) BG(0, 1); else BG(0, 0); }
#undef BG
}

// ================= fused attention (QK^T -> softmax -> PV) ==================
template<int CHECKQ>
__global__ __launch_bounds__(256) void fattn_k(
    const ushort_t* __restrict__ Q, int ldq, long sQb, long sQc,
    const ushort_t* __restrict__ K, int ldk, long sKb,
    const ushort_t* __restrict__ VT, long sVb,
    ushort_t* __restrict__ O, int ldo, long sOb, long sOc,
    int nc, int Mtot, const ushort_t* __restrict__ zbuf)
{
    __shared__ __align__(16) ushort_t Qs[128 * 64];
    __shared__ __align__(16) ushort_t Ks[128 * 64];
    __shared__ __align__(16) ushort_t Vs[64 * 128];
    __shared__ __align__(16) ushort_t Ps[128 * 128];
    int z = blockIdx.x;
    int c = z % nc, rr_ = z / nc;
    int h = rr_ % HH, b = rr_ / HH;
    int mQ = Mtot - c * 128;
    const ushort_t* Qb = Q + (long)b * sQb + (long)c * sQc + h * 64;
    const ushort_t* Kb = K + (long)b * sKb + h * 64;
    const ushort_t* Vb = VT + (long)b * sVb + (long)h * 64 * 128;
    ushort_t* Ob = O + (long)b * sOb + (long)c * sOc + h * 64;

    int tid = threadIdx.x, wid = tid >> 6, lane = tid & 63;
    int lr = lane & 15, lg = lane >> 4;

    {
        int rsub = lane >> 3, csub = lane & 7;
        #pragma unroll
        for (int i = 0; i < 4; i++) {
            int row = wid * 32 + i * 8 + rsub;
            int cc = (csub ^ rsub) * 8;
            const ushort_t* qs = (!CHECKQ || row < mQ) ? (Qb + (long)row * ldq + cc) : zbuf;
            gld16(qs, &Qs[(wid * 32 + i * 8) * 64]);
            gld16(Kb + (long)row * ldk + cc, &Ks[(wid * 32 + i * 8) * 64]);
        }
        int d4 = lane >> 4, c16 = lane & 15;
        #pragma unroll
        for (int i = 0; i < 4; i++) {
            int d = wid * 16 + i * 4 + d4;
            int cc = (c16 ^ (d & 7)) * 8;
            gld16(Vb + (long)d * 128 + cc, &Vs[(wid * 16 + i * 4) * 128]);
        }
    }
    __syncthreads();

    floatx4 acc[2][8];
    #pragma unroll
    for (int i = 0; i < 2; i++)
        #pragma unroll
        for (int j = 0; j < 8; j++)
            acc[i][j] = (floatx4){0.f, 0.f, 0.f, 0.f};
    const char* Qc = (const char*)Qs;
    const char* Kc = (const char*)Ks;
    #pragma unroll
    for (int kk = 0; kk < 2; kk++) {
        bhalf8 a_[2], b_[8];
        #pragma unroll
        for (int i = 0; i < 2; i++) {
            int r = wid * 32 + i * 16 + lr;
            a_[i] = *(const bhalf8*)(Qc + (r << 7) + ((((kk << 2) + lg) ^ (r & 7)) << 4));
        }
        #pragma unroll
        for (int j = 0; j < 8; j++) {
            int r = j * 16 + lr;
            b_[j] = *(const bhalf8*)(Kc + (r << 7) + ((((kk << 2) + lg) ^ (r & 7)) << 4));
        }
        #pragma unroll
        for (int i = 0; i < 2; i++)
            #pragma unroll
            for (int j = 0; j < 8; j++)
                acc[i][j] = __builtin_amdgcn_mfma_f32_16x16x32_bf16(
                    a_[i], b_[j], acc[i][j], 0, 0, 0);
    }

    #pragma unroll
    for (int i = 0; i < 2; i++) {
        #pragma unroll
        for (int r = 0; r < 4; r++) {
            int row = wid * 32 + i * 16 + lg * 4 + r;
            float v[8], m = -1e30f;
            #pragma unroll
            for (int j = 0; j < 8; j++) { v[j] = acc[i][j][r] * 0.125f; m = fmaxf(m, v[j]); }
            #pragma unroll
            for (int o = 8; o > 0; o >>= 1) m = fmaxf(m, __shfl_xor(m, o, 64));
            float s = 0.f;
            #pragma unroll
            for (int j = 0; j < 8; j++) { v[j] = expf(v[j] - m); s += v[j]; }
            #pragma unroll
            for (int o = 8; o > 0; o >>= 1) s += __shfl_xor(s, o, 64);
            float inv = 1.f / s;
            #pragma unroll
            for (int j = 0; j < 8; j++) {
                int col = j * 16 + lr;
                int byte = (row << 8) + ((((col >> 3) ^ (row & 7)) << 4)) + ((col & 7) << 1);
                *(ushort_t*)((char*)Ps + byte) = f2b(v[j] * inv);
            }
        }
    }
    __syncthreads();

    floatx4 acc2[2][4];
    #pragma unroll
    for (int i = 0; i < 2; i++)
        #pragma unroll
        for (int j = 0; j < 4; j++)
            acc2[i][j] = (floatx4){0.f, 0.f, 0.f, 0.f};
    const char* Pc = (const char*)Ps;
    const char* Vc = (const char*)Vs;
    #pragma unroll
    for (int kk = 0; kk < 4; kk++) {
        bhalf8 a_[2], b_[4];
        #pragma unroll
        for (int i = 0; i < 2; i++) {
            int r = wid * 32 + i * 16 + lr;
            a_[i] = *(const bhalf8*)(Pc + (r << 8) + ((((kk << 2) + lg) ^ (r & 7)) << 4));
        }
        #pragma unroll
        for (int j = 0; j < 4; j++) {
            int d = j * 16 + lr;
            b_[j] = *(const bhalf8*)(Vc + (d << 8) + ((((kk << 2) + lg) ^ (d & 7)) << 4));
        }
        #pragma unroll
        for (int i = 0; i < 2; i++)
            #pragma unroll
            for (int j = 0; j < 4; j++)
                acc2[i][j] = __builtin_amdgcn_mfma_f32_16x16x32_bf16(
                    a_[i], b_[j], acc2[i][j], 0, 0, 0);
    }
    #pragma unroll
    for (int i = 0; i < 2; i++) {
        #pragma unroll
        for (int r = 0; r < 4; r++) {
            int q = wid * 32 + i * 16 + lg * 4 + r;
            if (CHECKQ && q >= mQ) continue;
            #pragma unroll
            for (int j = 0; j < 4; j++) {
                int d = j * 16 + lr;
                Ob[(long)q * ldo + d] = f2b(acc2[i][j][r]);
            }
        }
    }
}

// ================= fp32 tiled GEMM (logits only) =================
template<int TRANSB>
__global__ __launch_bounds__(256) void gemm_k(
    const float* __restrict__ A, int lda,
    const float* __restrict__ B, int ldb,
    float* __restrict__ C, int ldc,
    int M, int N, int K)
{
    __shared__ float As[16][68];
    __shared__ float Bs[16][68];
    int m0 = blockIdx.y * 64, n0 = blockIdx.x * 64;
    int tid = threadIdx.x;
    int tr = tid / 16, tc = tid % 16;
    float acc[4][4] = {};
    for (int k0 = 0; k0 < K; k0 += 16) {
        {
            int ar = tid / 4;
            int ac = (tid % 4) * 4;
            int gm = m0 + ar;
            #pragma unroll
            for (int i = 0; i < 4; i++) {
                int gk = k0 + ac + i;
                As[ac + i][ar] = (gm < M && gk < K) ? A[(long)gm * lda + gk] : 0.f;
            }
        }
        {
            int bn = tid / 4;
            int bk = (tid % 4) * 4;
            int gn = n0 + bn;
            #pragma unroll
            for (int i = 0; i < 4; i++) {
                int gk = k0 + bk + i;
                Bs[bk + i][bn] = (gn < N && gk < K) ? B[(long)gn * ldb + gk] : 0.f;
            }
        }
        __syncthreads();
        #pragma unroll
        for (int kk = 0; kk < 16; kk++) {
            float a[4], b[4];
            #pragma unroll
            for (int i = 0; i < 4; i++) a[i] = As[kk][tr * 4 + i];
            #pragma unroll
            for (int i = 0; i < 4; i++) b[i] = Bs[kk][tc * 4 + i];
            #pragma unroll
            for (int i = 0; i < 4; i++)
                #pragma unroll
                for (int j = 0; j < 4; j++)
                    acc[i][j] += a[i] * b[j];
        }
        __syncthreads();
    }
    #pragma unroll
    for (int i = 0; i < 4; i++) {
        int gm = m0 + tr * 4 + i;
        if (gm >= M) continue;
        #pragma unroll
        for (int j = 0; j < 4; j++) {
            int gn = n0 + tc * 4 + j;
            if (gn >= N) continue;
            C[(long)gm * ldc + gn] = acc[i][j];
        }
    }
}

// ================= conversions =================
__global__ void f2b_k(const float* __restrict__ in, ushort_t* __restrict__ out, long n) {
    long stride = (long)gridDim.x * blockDim.x * 8;
    for (long i = ((long)blockIdx.x * blockDim.x + threadIdx.x) * 8; i < n; i += stride) {
        float4 a = *(const float4*)(in + i);
        float4 b = *(const float4*)(in + i + 4);
        uint4 o;
        o.x = (unsigned)f2b(a.x) | ((unsigned)f2b(a.y) << 16);
        o.y = (unsigned)f2b(a.z) | ((unsigned)f2b(a.w) << 16);
        o.z = (unsigned)f2b(b.x) | ((unsigned)f2b(b.y) << 16);
        o.w = (unsigned)f2b(b.z) | ((unsigned)f2b(b.w) << 16);
        *(uint4*)(out + i) = o;
    }
}
__global__ void add_f2b_k(const float* __restrict__ a, const float* __restrict__ b,
                          ushort_t* __restrict__ out, long n) {
    long stride = (long)gridDim.x * blockDim.x * 8;
    for (long i = ((long)blockIdx.x * blockDim.x + threadIdx.x) * 8; i < n; i += stride) {
        float4 x = *(const float4*)(a + i);
        float4 y = *(const float4*)(b + i);
        float4 x2 = *(const float4*)(a + i + 4);
        float4 y2 = *(const float4*)(b + i + 4);
        uint4 o;
        o.x = (unsigned)f2b(x.x + y.x) | ((unsigned)f2b(x.y + y.y) << 16);
        o.y = (unsigned)f2b(x.z + y.z) | ((unsigned)f2b(x.w + y.w) << 16);
        o.z = (unsigned)f2b(x2.x + y2.x) | ((unsigned)f2b(x2.y + y2.y) << 16);
        o.w = (unsigned)f2b(x2.z + y2.z) | ((unsigned)f2b(x2.w + y2.w) << 16);
        *(uint4*)(out + i) = o;
    }
}
// transpose+convert fp32 (R x C) -> bf16 (C x R), batched over z
__global__ void f2b_t_k(const float* __restrict__ in, ushort_t* __restrict__ out,
                        int R, int C, long inStride, long outStride) {
    __shared__ float tile[32][33];
    int z = blockIdx.z;
    in += (long)z * inStride;
    out += (long)z * outStride;
    int c0 = blockIdx.x * 32, r0 = blockIdx.y * 32;
    int tx = threadIdx.x, ty = threadIdx.y;
    #pragma unroll
    for (int i = 0; i < 32; i += 8) {
        int r = r0 + ty + i, c = c0 + tx;
        tile[ty + i][tx] = (r < R && c < C) ? in[(long)r * C + c] : 0.f;
    }
    __syncthreads();
    #pragma unroll
    for (int i = 0; i < 32; i += 8) {
        int c = c0 + ty + i, r = r0 + tx;
        if (c < C && r < R) out[(long)c * R + r] = f2b(tile[tx][ty + i]);
    }
}
// bf16 transpose: in (R x C, ldin) -> out (C x R), batched over z
__global__ void t_bf_k(const ushort_t* __restrict__ in, ushort_t* __restrict__ out,
                       int R, int C, int ldin, long inStride, long outStride) {
    __shared__ ushort_t tile[32][33];
    int z = blockIdx.z;
    in += (long)z * inStride;
    out += (long)z * outStride;
    int c0 = blockIdx.x * 32, r0 = blockIdx.y * 32;
    int tx = threadIdx.x, ty = threadIdx.y;
    #pragma unroll
    for (int i = 0; i < 32; i += 8) {
        int r = r0 + ty + i, c = c0 + tx;
        if (r < R && c < C) tile[ty + i][tx] = in[(long)r * ldin + c];
    }
    __syncthreads();
    #pragma unroll
    for (int i = 0; i < 32; i += 8) {
        int c = c0 + ty + i, r = r0 + tx;
        if (c < C && r < R) out[(long)c * R + r] = tile[tx][ty + i];
    }
}
__global__ void cat3all_k(float* __restrict__ dst, const float* __restrict__ a,
                          const float* __restrict__ b, const float* __restrict__ c) {
    int i = blockIdx.x * blockDim.x + threadIdx.x;
    if (i >= LL * 1536) return;
    int l = i / 1536, j = i % 1536;
    float v = (j < 512) ? a[l * 512 + j]
            : (j < 1024) ? b[l * 512 + j - 512] : c[l * 512 + j - 1024];
    dst[i] = v;
}

// ---------------- elementwise ----------------
__global__ void addpos_bf_k(const float* __restrict__ a, const float* __restrict__ pos,
                            float* __restrict__ o, ushort_t* __restrict__ obf,
                            long n, long pmod) {
    for (long i = blockIdx.x * (long)blockDim.x + threadIdx.x; i < n;
         i += (long)gridDim.x * blockDim.x) {
        float v = a[i] + pos[i % pmod];
        o[i] = v;
        obf[i] = f2b(v);
    }
}
__global__ void zero_k(float* __restrict__ p, long n) {
    for (long i = blockIdx.x * (long)blockDim.x + threadIdx.x; i < n;
         i += (long)gridDim.x * blockDim.x)
        p[i] = 0.f;
}
__global__ void sentinel_k(float* p) { p[0] = 1e9f; }
// zero pad rows r=0 and r=129 of a (B,130,CO) channel-last buffer
__global__ void padzero_k(ushort_t* __restrict__ h, int CO) {
    int b = blockIdx.x;
    for (int i = threadIdx.x; i < CO; i += blockDim.x) {
        h[(long)b * 130 * CO + i] = 0;
        h[((long)b * 130 + 129) * CO + i] = 0;
    }
}

// ---------------- residual + layernorm ----------------
__global__ __launch_bounds__(256) void ln_res_k(float* __restrict__ x,
                                                const float* __restrict__ z,
                                                ushort_t* __restrict__ xbf,
                                                const float* __restrict__ g,
                                                const float* __restrict__ b) {
    long row = blockIdx.x;
    float* px = x + row * DD;
    const float* pz = z + row * DD;
    ushort_t* pb = xbf + row * DD;
    int t = threadIdx.x;
    float v0 = px[t] + pz[t];
    float v1 = px[t + 256] + pz[t + 256];
    float s = v0 + v1, sq = v0 * v0 + v1 * v1;
    for (int o = 32; o > 0; o >>= 1) {
        s += __shfl_xor(s, o, 64);
        sq += __shfl_xor(sq, o, 64);
    }
    __shared__ float ss[4], sqq[4];
    int wave = t >> 6, lane = t & 63;
    if (lane == 0) { ss[wave] = s; sqq[wave] = sq; }
    __syncthreads();
    s = ss[0] + ss[1] + ss[2] + ss[3];
    sq = sqq[0] + sqq[1] + sqq[2] + sqq[3];
    float mean = s * (1.f / DD);
    float var = sq * (1.f / DD) - mean * mean;
    float rstd = 1.f / sqrtf(var + 1e-5f);
    float o0 = (v0 - mean) * rstd * g[t] + b[t];
    float o1 = (v1 - mean) * rstd * g[t + 256] + b[t + 256];
    px[t] = o0;
    px[t + 256] = o1;
    pb[t] = f2b(o0);
    pb[t + 256] = f2b(o1);
}

// ---------------- conv helpers ----------------
__global__ void pad_copy_bf_k(const float* __restrict__ fp, ushort_t* __restrict__ fpp) {
    long total = (long)BB * TT * NW;
    for (long i = blockIdx.x * (long)blockDim.x + threadIdx.x; i < total;
         i += (long)gridDim.x * blockDim.x) {
        long ci = i % NW;
        long r = i / NW;
        long t = r % TT;
        long b = r / TT;
        fpp[(b * 130 + t + 1) * NW + ci] = f2b(fp[i]);
    }
}
__global__ void repack_bf_k(const float* __restrict__ w, ushort_t* __restrict__ wk,
                            int CO, int CI) {
    long total = (long)CO * CI * 3;
    for (long i = blockIdx.x * (long)blockDim.x + threadIdx.x; i < total;
         i += (long)gridDim.x * blockDim.x) {
        long kt = i % 3;
        long r = i / 3;
        long ci = r % CI;
        long co = r / CI;
        wk[kt * (long)CO * CI + co * CI + ci] = f2b(w[i]);
    }
}
__global__ __launch_bounds__(128) void conv5_bf_k(const ushort_t* __restrict__ h4,
                                                  const float* __restrict__ w,
                                                  const float* __restrict__ bias,
                                                  float* __restrict__ out) {
    int b = blockIdx.x, t = threadIdx.x;
    __shared__ float wsm[384];
    wsm[t] = w[t];
    wsm[t + 128] = w[t + 128];
    wsm[t + 256] = w[t + 256];
    __syncthreads();
    const ushort_t* hb = h4 + (long)b * 130 * 128;
    float acc = bias[0];
    for (int ci = 0; ci < 128; ci++) {
        float w0 = wsm[ci * 3], w1 = wsm[ci * 3 + 1], w2 = wsm[ci * 3 + 2];
        acc += w0 * b2f(hb[(t + 0) * 128 + ci]) + w1 * b2f(hb[(t + 1) * 128 + ci]) +
               w2 * b2f(hb[(t + 2) * 128 + ci]);
    }
    out[b * TT + t] = 1.f / (1.f + expf(-acc));
}

// ---------------- masked segment softmax pooling ----------------
__global__ __launch_bounds__(128) void seg_pool_k(const float* __restrict__ weights,
                                                  const int* __restrict__ steds,
                                                  const float* __restrict__ vid,
                                                  float* __restrict__ segf) {
    int b = blockIdx.y, sidx = blockIdx.x;
    int st = steds[(b * SS + sidx) * 2];
    int ed = steds[(b * SS + sidx) * 2 + 1];
    int t = threadIdx.x;
    float w = (t >= st && t <= ed) ? weights[b * TT + t] : -1e30f;
    __shared__ float red[2];
    __shared__ float aw[TT];
    int wave = t >> 6, lane = t & 63;
    float m = w;
    for (int o = 32; o > 0; o >>= 1) m = fmaxf(m, __shfl_xor(m, o, 64));
    if (lane == 0) red[wave] = m;
    __syncthreads();
    m = fmaxf(red[0], red[1]);
    float e = expf(w - m);
    float sum = e;
    for (int o = 32; o > 0; o >>= 1) sum += __shfl_xor(sum, o, 64);
    __syncthreads();
    if (lane == 0) red[wave] = sum;
    __syncthreads();
    sum = red[0] + red[1];
    aw[t] = e / sum;
    __syncthreads();
    #pragma unroll
    for (int i = 0; i < 4; i++) {
        int d = t + i * 128;
        float acc = 0.f;
        for (int tt = 0; tt < TT; tt++)
            acc += aw[tt] * vid[((long)b * TT + tt) * DD + d];
        segf[((long)b * SS + sidx) * DD + d] = acc;
    }
}

extern "C" void kernel_launch(void* const* d_in, const int* in_sizes, int n_in,
                              void* d_out, int out_size, void* d_ws, size_t ws_size,
                              hipStream_t stream) {
    const float* vid = (const float*)d_in[0];
    const float* actn_feats = (const float*)d_in[2];
    const float* actn_concepts = (const float*)d_in[3];
    const float* pos = (const float*)d_in[4];
    const float* Wq = (const float*)d_in[5];
    const float* bq = (const float*)d_in[6];
    const float* Wk = (const float*)d_in[7];
    const float* bk = (const float*)d_in[8];
    const float* Wv = (const float*)d_in[9];
    const float* bv = (const float*)d_in[10];
    const float* Wo = (const float*)d_in[11];
    const float* bo = (const float*)d_in[12];
    const float* W1 = (const float*)d_in[13];
    const float* b1 = (const float*)d_in[14];
    const float* W2 = (const float*)d_in[15];
    const float* b2 = (const float*)d_in[16];
    const float* g1 = (const float*)d_in[17];
    const float* bb1 = (const float*)d_in[18];
    const float* g2 = (const float*)d_in[19];
    const float* bb2 = (const float*)d_in[20];
    const float* pqW = (const float*)d_in[21];
    const float* pqb = (const float*)d_in[22];
    const float* pkW = (const float*)d_in[23];
    const float* pkb = (const float*)d_in[24];
    const float* pvW = (const float*)d_in[25];
    const float* pvb = (const float*)d_in[26];
    const float* c1w = (const float*)d_in[27];
    const float* c1b = (const float*)d_in[28];
    const float* c2w = (const float*)d_in[29];
    const float* c2b = (const float*)d_in[30];
    const float* c3w = (const float*)d_in[31];
    const float* c3b = (const float*)d_in[32];
    const float* c4w = (const float*)d_in[33];
    const float* c4b = (const float*)d_in[34];
    const float* c5w = (const float*)d_in[35];
    const float* c5b = (const float*)d_in[36];
    const int* steds = (const int*)d_in[37];

    float* out = (float*)d_out;
    float* fc_out = out;            // 32*128
    float* al_out = out + 4096;     // 32*8*200
    float* fp_out = out + 55296;    // 32*128*2000

    float* ws = (float*)d_ws;
    const long NEED = 25165824;  // floats (96 MiB)
    if (ws_size < (size_t)NEED * 4) {
        sentinel_k<<<1, 1, 0, stream>>>(fc_out);
        return;
    }

    // ---- arena (float-unit offsets) ----
    // phase A:
    const long A_XBF   = 0;          // x bf16 (1,048,576)
    const long A_QKVBF = 1048576;    // qkv bf16 (3,145,728) -> 4,194,304
    const long A_VT    = 4194304;    // vT bf16 (1,048,576) -> 5,242,880
    const long A_FFH   = 7340032;    // ffh bf16 (4,194,304) -> 11,534,336
    const long A_AOBF  = 11534336;   // attn out bf16 (1,048,576) -> 12,582,912
    const long A_QB    = 12582912;   // fp32 scratch (2,097,152) -> 14,680,064
    const long A_QKVT  = 14680064;   // -> 16,252,928
    const long A_WOT   = 16252928;   // -> 16,777,216
    const long A_W1T   = 16777216;   // -> 18,874,368
    const long A_W2T   = 18874368;   // -> 20,971,520
    const long A_QKVB  = 20971520;   // -> 20,977,664
    const long XB      = 21000192;   // x fp32 -> 23,097,344
    // phase B:
    const long B_UPD   = 0;          // upd bf16 full (16,384,000) -> 16,384,000
    const long B_VPRBF = 16384000;   // vproj bf16 -> 17,432,576
    const long B_PW    = 17432576;   // -> 17,825,792
    const long B_ACBF  = 17825792;   // -> 18,337,792
    const long B_QPBF  = 18337792;   // -> 18,849,792
    const long B_KPBF  = 18849792;   // -> 19,898,368
    const long B_VP    = 19898368;   // Vp fp32 -> 21,995,520
    const long B_VPT   = 21995520;   // VpT bf16 -> 23,044,096
    // phase C:
    const long C_FPP   = 0;
    const long C_WK1   = 4160000;
    const long C_WK2   = 7232000;
    const long C_WK3   = 8018432;
    const long C_WK4   = 8215040;
    const long C_H1    = 8264192;
    const long C_H2    = 10394112;
    const long C_H3    = 11459072;
    const long C_H4    = 11991552;
    const long C_SEGF  = 12257792;   // -> 12,388,864
    const long ZPAD    = 25165760;   // zbuf (64 floats)

    float* xb = ws + XB;
    const ushort_t* zbuf = (const ushort_t*)(ws + ZPAD);
    const long nBTD = (long)BB * TT * DD;

    zero_k<<<1, 64, 0, stream>>>(ws + ZPAD, 64);

    ushort_t* xbf = (ushort_t*)(ws + A_XBF);
    addpos_bf_k<<<2048, 256, 0, stream>>>(vid, pos, xb, xbf, nBTD, (long)TT * DD);

    // ---- all-layer weight prep ----
    ushort_t* qkvT = (ushort_t*)(ws + A_QKVT);
    ushort_t* WoT  = (ushort_t*)(ws + A_WOT);
    ushort_t* W1T  = (ushort_t*)(ws + A_W1T);
    ushort_t* W2T  = (ushort_t*)(ws + A_W2T);
    float*    qkvb = ws + A_QKVB;
    dim3 tblk(32, 8);
    f2b_t_k<<<dim3(16, 16, LL), tblk, 0, stream>>>(Wq, qkvT, DD, DD, (long)DD * DD, 786432);
    f2b_t_k<<<dim3(16, 16, LL), tblk, 0, stream>>>(Wk, qkvT + 262144, DD, DD, (long)DD * DD, 786432);
    f2b_t_k<<<dim3(16, 16, LL), tblk, 0, stream>>>(Wv, qkvT + 524288, DD, DD, (long)DD * DD, 786432);
    f2b_t_k<<<dim3(16, 16, LL), tblk, 0, stream>>>(Wo, WoT, DD, DD, (long)DD * DD, 262144);
    f2b_t_k<<<dim3(64, 16, LL), tblk, 0, stream>>>(W1, W1T, DD, FF, (long)DD * FF, 1048576);
    f2b_t_k<<<dim3(16, 64, LL), tblk, 0, stream>>>(W2, W2T, FF, DD, (long)FF * DD, 1048576);
    cat3all_k<<<(LL * 1536 + 255) / 256, 256, 0, stream>>>(qkvb, bq, bk, bv);

    // ================= phase A: transformer =================
    ushort_t* qkvbf = (ushort_t*)(ws + A_QKVBF);
    ushort_t* vTb   = (ushort_t*)(ws + A_VT);
    ushort_t* ffhbf = (ushort_t*)(ws + A_FFH);
    ushort_t* aobf  = (ushort_t*)(ws + A_AOBF);
    float*    qb    = ws + A_QB;

    for (int l = 0; l < LL; l++) {
        launch_bgemm(0, 1, xbf, DD, 0, 0, qkvT + (long)l * 786432, DD, 0, 0,
                     qkvbf, 1536, 0, 0, qkvb + (long)l * 1536,
                     BB * TT, 1536, DD, 1.f, 1, 1, 1, 0, 0, zbuf, stream);
        t_bf_k<<<dim3(16, 4, BB), tblk, 0, stream>>>(qkvbf + 1024, vTb, TT, DD, 1536,
                                                     (long)TT * 1536, (long)DD * TT);
        fattn_k<0><<<BB * HH, 256, 0, stream>>>(
            qkvbf, 1536, (long)TT * 1536, 0,
            qkvbf + 512, 1536, (long)TT * 1536,
            vTb, (long)DD * TT,
            aobf, DD, (long)TT * DD, 0, 1, TT, zbuf);
        launch_bgemm(0, 0, aobf, DD, 0, 0, WoT + (long)l * 262144, DD, 0, 0,
                     qb, DD, 0, 0, bo + (long)l * DD,
                     BB * TT, DD, DD, 1.f, 1, 1, 1, 0, 0, zbuf, stream);
        ln_res_k<<<BB * TT, 256, 0, stream>>>(xb, qb, xbf, g1 + (long)l * DD, bb1 + (long)l * DD);
        launch_bgemm(1, 1, xbf, DD, 0, 0, W1T + (long)l * 1048576, DD, 0, 0,
                     ffhbf, FF, 0, 0, b1 + (long)l * FF,
                     BB * TT, FF, DD, 1.f, 1, 1, 1, 0, 0, zbuf, stream);
        launch_bgemm(0, 0, ffhbf, FF, 0, 0, W2T + (long)l * 1048576, FF, 0, 0,
                     qb, DD, 0, 0, b2 + (long)l * DD,
                     BB * TT, DD, FF, 1.f, 1, 1, 1, 0, 0, zbuf, stream);
        ln_res_k<<<BB * TT, 256, 0, stream>>>(xb, qb, xbf, g2 + (long)l * DD, bb2 + (long)l * DD);
    }

    // ================= phase B: cross-attn + feats_proj =================
    ushort_t* updbf = (ushort_t*)(ws + B_UPD);
    ushort_t* vprbf = (ushort_t*)(ws + B_VPRBF);
    ushort_t* pqT   = (ushort_t*)(ws + B_PW);
    ushort_t* pkT   = (ushort_t*)(ws + B_PW + 131072);
    ushort_t* pvT   = (ushort_t*)(ws + B_PW + 262144);
    ushort_t* acbf  = (ushort_t*)(ws + B_ACBF);
    ushort_t* Qpbf  = (ushort_t*)(ws + B_QPBF);
    ushort_t* Kpbf  = (ushort_t*)(ws + B_KPBF);
    float*    Vp    = ws + B_VP;
    ushort_t* VpT   = (ushort_t*)(ws + B_VPT);

    add_f2b_k<<<1024, 256, 0, stream>>>(vid, xb, vprbf, nBTD);   // xb dead after
    f2b_t_k<<<dim3(16, 16, 1), tblk, 0, stream>>>(pqW, pqT, DD, DD, 0, 0);
    f2b_t_k<<<dim3(16, 16, 1), tblk, 0, stream>>>(pkW, pkT, DD, DD, 0, 0);
    f2b_t_k<<<dim3(16, 16, 1), tblk, 0, stream>>>(pvW, pvT, DD, DD, 0, 0);
    f2b_k<<<512, 256, 0, stream>>>(actn_concepts, acbf, (long)NW * DD);

    launch_bgemm(0, 1, acbf, DD, 0, 0, pqT, DD, 0, 0, Qpbf, DD, 0, 0,
                 pqb, NW, DD, DD, 1.f, 1, 1, 1, 0, 0, zbuf, stream);
    launch_bgemm(0, 1, vprbf, DD, 0, 0, pkT, DD, 0, 0, Kpbf, DD, 0, 0,
                 pkb, BB * TT, DD, DD, 1.f, 1, 1, 1, 0, 0, zbuf, stream);
    launch_bgemm(0, 0, vprbf, DD, 0, 0, pvT, DD, 0, 0, Vp, DD, 0, 0,
                 pvb, BB * TT, DD, DD, 1.f, 1, 1, 1, 0, 0, zbuf, stream);
    f2b_t_k<<<dim3(16, 4, BB), tblk, 0, stream>>>(Vp, VpT, TT, DD, (long)TT * DD, (long)TT * DD);

    // fused cross-attention: one launch, 16 concept-chunks of 128
    fattn_k<1><<<BB * HH * 16, 256, 0, stream>>>(
        Qpbf, DD, 0, (long)128 * DD,
        Kpbf, DD, (long)TT * DD,
        VpT, (long)DD * TT,
        updbf, DD, (long)NW * DD, (long)128 * DD, 16, NW, zbuf);

    // feats_proj: fp[b,t,n] = vproj[b,t,:] . upd[b,n,:]
    launch_bgemm(0, 0, vprbf, DD, (long)TT * DD, 0,
                 updbf, DD, (long)NW * DD, 0,
                 fp_out, NW, (long)TT * NW, 0,
                 nullptr, TT, NW, DD, 1.f, 1, BB, 1, 0, 0, zbuf, stream);

    // ================= phase C: conv tower (merged-M, taps as row shifts) ===
    ushort_t* fpp = (ushort_t*)(ws + C_FPP);
    ushort_t* wk1 = (ushort_t*)(ws + C_WK1);
    ushort_t* wk2 = (ushort_t*)(ws + C_WK2);
    ushort_t* wk3 = (ushort_t*)(ws + C_WK3);
    ushort_t* wk4 = (ushort_t*)(ws + C_WK4);
    ushort_t* h1  = (ushort_t*)(ws + C_H1);
    ushort_t* h2  = (ushort_t*)(ws + C_H2);
    ushort_t* h3  = (ushort_t*)(ws + C_H3);
    ushort_t* h4  = (ushort_t*)(ws + C_H4);

    repack_bf_k<<<1024, 256, 0, stream>>>(c1w, wk1, 1024, NW);
    repack_bf_k<<<512, 256, 0, stream>>>(c2w, wk2, 512, 1024);
    repack_bf_k<<<256, 256, 0, stream>>>(c3w, wk3, 256, 512);
    repack_bf_k<<<128, 256, 0, stream>>>(c4w, wk4, 128, 256);
    padzero_k<<<BB, 256, 0, stream>>>(fpp, NW);
    pad_copy_bf_k<<<2048, 256, 0, stream>>>(fp_out, fpp);

    const int MROWS = BB * 130 - 2;  // 4158: out row gm -> padded row gm+1
    launch_bgemm(1, 1, fpp, NW, 0, 0, wk1, NW, 0, 0,
                 h1 + 1024, 1024, 0, 0, c1b,
                 MROWS, 1024, NW, 1.f, 1, 1, 3, NW, (long)1024 * NW, zbuf, stream);
    padzero_k<<<BB, 256, 0, stream>>>(h1, 1024);
    launch_bgemm(1, 1, h1, 1024, 0, 0, wk2, 1024, 0, 0,
                 h2 + 512, 512, 0, 0, c2b,
                 MROWS, 512, 1024, 1.f, 1, 1, 3, 1024, (long)512 * 1024, zbuf, stream);
    padzero_k<<<BB, 256, 0, stream>>>(h2, 512);
    launch_bgemm(1, 1, h2, 512, 0, 0, wk3, 512, 0, 0,
                 h3 + 256, 256, 0, 0, c3b,
                 MROWS, 256, 512, 1.f, 1, 1, 3, 512, (long)256 * 512, zbuf, stream);
    padzero_k<<<BB, 256, 0, stream>>>(h3, 256);
    launch_bgemm(1, 1, h3, 256, 0, 0, wk4, 256, 0, 0,
                 h4 + 128, 128, 0, 0, c4b,
                 MROWS, 128, 256, 1.f, 1, 1, 3, 256, (long)128 * 256, zbuf, stream);
    padzero_k<<<BB, 256, 0, stream>>>(h4, 128);
    conv5_bf_k<<<BB, 128, 0, stream>>>(h4, c5w, c5b, fc_out);

    // ================= segment pooling + logits (fp32) =================
    float* segf = ws + C_SEGF;
    seg_pool_k<<<dim3(SS, BB), 128, 0, stream>>>(fc_out, steds, vid, segf);
    gemm_k<1><<<dim3((NCC + 63) / 64, (BB * SS + 63) / 64, 1), 256, 0, stream>>>(
        segf, DD, actn_feats, DD, al_out, NCC, BB * SS, NCC, DD);
}

// Round 9
// 1150.764 us; speedup vs baseline: 1.2246x; 1.2246x over previous
//
#include <hip/hip_runtime.h>
#include <hip/hip_bf16.h>

// ---------------- constants ----------------
#define BB 32
#define TT 128
#define DD 512
#define NW 2000
#define NCC 200
#define SS 8
#define LL 4
#define HH 8
#define FF 2048
#define HD 64

typedef unsigned short ushort_t;
typedef __attribute__((ext_vector_type(8))) short bhalf8;
typedef __attribute__((ext_vector_type(4))) float floatx4;

__device__ inline ushort_t f2b(float x) {
    union { float f; unsigned int u; } v; v.f = x;
    unsigned int r = (v.u + 0x7FFFu + ((v.u >> 16) & 1u)) >> 16;
    return (ushort_t)r;
}
__device__ inline float b2f(ushort_t u) {
    union { unsigned int u; float f; } v; v.u = ((unsigned int)u) << 16;
    return v.f;
}
__device__ inline void gld16(const ushort_t* g, ushort_t* l) {
    __builtin_amdgcn_global_load_lds(
        (const __attribute__((address_space(1))) void*)g,
        (__attribute__((address_space(3))) void*)l, 16, 0, 0);
}

// ================= bf16 MFMA GEMM (dbuf pipelined, swizzled LDS) ============
// C[M,N] = act( alpha * sum_tap A[M,K] @ B[N,K]^T + bias )
// Tile TM x TN; 4 waves in WM x (4/WM) grid. TM,TN in {64,128}.
// batch z: zb=z/batchH, zh=z%batchH; offsets sA1*zb+sA2*zh etc (elements).
template<int TM, int TN, int WM, int ACT, int OUTBF>
__global__ __launch_bounds__(256) void bgemm_k(
    const ushort_t* __restrict__ A, int lda, long sA1, long sA2,
    const ushort_t* __restrict__ B, int ldb, long sB1, long sB2,
    void* __restrict__ Cv, int ldc, long sC1, long sC2,
    const float* __restrict__ bias,
    int M, int N, int K, float alpha, int batchH,
    int taps, long tapA, long tapB, const ushort_t* __restrict__ zbuf)
{
    constexpr int WN = 4 / WM;
    constexpr int RI = TM / WM / 16;   // A frags per wave
    constexpr int CJ = TN / WN / 16;   // B frags per wave
    constexpr int AI = TM / 32;        // A stage gld16 per wave
    constexpr int BI = TN / 32;        // B stage gld16 per wave
    __shared__ __align__(16) ushort_t sm[2][(TM + TN) * 64];
    int z = blockIdx.z;
    int zb = z / batchH, zh = z % batchH;
    A += (long)zb * sA1 + (long)zh * sA2;
    B += (long)zb * sB1 + (long)zh * sB2;
    long cOff = (long)zb * sC1 + (long)zh * sC2;
    int m0 = blockIdx.y * TM, n0 = blockIdx.x * TN;
    int tid = threadIdx.x;
    int wid = tid >> 6, lane = tid & 63;
    int wr = wid % WM, wc = wid / WM;
    int lr = lane & 15, lg = lane >> 4;

    int kSteps = (K + 63) >> 6;
    int nt = taps * kSteps;

    int rsub = lane >> 3;
    int ssub = lane & 7;
    int scol = ((ssub ^ rsub) << 3);      // pre-swizzled logical col (bf16)
    bool aok[AI], bok[BI];
    const ushort_t* aptr[AI];
    const ushort_t* bptr[BI];
    #pragma unroll
    for (int i = 0; i < AI; i++) {
        int row = wid * (TM / 4) + i * 8 + rsub;
        aok[i] = (m0 + row) < M;
        aptr[i] = A + (long)(m0 + row) * lda + scol;
    }
    #pragma unroll
    for (int i = 0; i < BI; i++) {
        int row = wid * (TN / 4) + i * 8 + rsub;
        bok[i] = (n0 + row) < N;
        bptr[i] = B + (long)(n0 + row) * ldb + scol;
    }

    floatx4 acc[RI][CJ];
    #pragma unroll
    for (int i = 0; i < RI; i++)
        #pragma unroll
        for (int j = 0; j < CJ; j++)
            acc[i][j] = (floatx4){0.f, 0.f, 0.f, 0.f};

    // prologue: stage tile 0 into buffer 0
    {
        bool kOk = scol < K;
        #pragma unroll
        for (int i = 0; i < AI; i++) {
            const ushort_t* as = (kOk && aok[i]) ? aptr[i] : zbuf;
            gld16(as, &sm[0][(wid * (TM / 4) + i * 8) * 64]);
        }
        #pragma unroll
        for (int i = 0; i < BI; i++) {
            const ushort_t* bs = (kOk && bok[i]) ? bptr[i] : zbuf;
            gld16(bs, &sm[0][TM * 64 + (wid * (TN / 4) + i * 8) * 64]);
        }
    }
    __syncthreads();

    int cur = 0;
    int tap_n = 0, k0_n = 0;
    for (int t = 0; t < nt; t++) {
        // advance to step t+1 and prefetch into other buffer
        k0_n += 64;
        if (k0_n >= K) { k0_n = 0; ++tap_n; }
        if (tap_n < taps) {
            bool kOk = (k0_n + scol) < K;
            #pragma unroll
            for (int i = 0; i < AI; i++) {
                const ushort_t* as =
                    (kOk && aok[i]) ? (aptr[i] + (long)tap_n * tapA + k0_n) : zbuf;
                gld16(as, &sm[cur ^ 1][(wid * (TM / 4) + i * 8) * 64]);
            }
            #pragma unroll
            for (int i = 0; i < BI; i++) {
                const ushort_t* bs =
                    (kOk && bok[i]) ? (bptr[i] + (long)tap_n * tapB + k0_n) : zbuf;
                gld16(bs, &sm[cur ^ 1][TM * 64 + (wid * (TN / 4) + i * 8) * 64]);
            }
        }
        // compute on current buffer (swizzled ds_read)
        const char* Ab = (const char*)&sm[cur][0];
        const char* Bbs = (const char*)&sm[cur][TM * 64];
        #pragma unroll
        for (int kk = 0; kk < 2; kk++) {
            bhalf8 a_[RI], b_[CJ];
            #pragma unroll
            for (int i = 0; i < RI; i++) {
                int r = wr * (TM / WM) + i * 16 + lr;
                int off = (r << 7) + (((kk << 6) + (lg << 4)) ^ ((r & 7) << 4));
                a_[i] = *(const bhalf8*)(Ab + off);
            }
            #pragma unroll
            for (int j = 0; j < CJ; j++) {
                int r = wc * (TN / WN) + j * 16 + lr;
                int off = (r << 7) + (((kk << 6) + (lg << 4)) ^ ((r & 7) << 4));
                b_[j] = *(const bhalf8*)(Bbs + off);
            }
            #pragma unroll
            for (int i = 0; i < RI; i++)
                #pragma unroll
                for (int j = 0; j < CJ; j++)
                    acc[i][j] = __builtin_amdgcn_mfma_f32_16x16x32_bf16(
                        a_[i], b_[j], acc[i][j], 0, 0, 0);
        }
        __syncthreads();   // drains vmcnt (prefetch) + lgkm; swap safe
        cur ^= 1;
    }

    // epilogue: C/D layout col=lane&15, row=(lane>>4)*4+reg
    #pragma unroll
    for (int i = 0; i < RI; i++) {
        int gm_base = m0 + wr * (TM / WM) + i * 16 + lg * 4;
        #pragma unroll
        for (int j = 0; j < CJ; j++) {
            int gn = n0 + wc * (TN / WN) + j * 16 + lr;
            if (gn >= N) continue;
            float bv = bias ? bias[gn] : 0.f;
            #pragma unroll
            for (int r = 0; r < 4; r++) {
                int gm = gm_base + r;
                if (gm >= M) continue;
                float v = acc[i][j][r] * alpha + bv;
                if (ACT == 1) v = fmaxf(v, 0.f);
                long idx = cOff + (long)gm * ldc + gn;
                if (OUTBF) ((ushort_t*)Cv)[idx] = f2b(v);
                else       ((float*)Cv)[idx] = v;
            }
        }
    }
}

template<int TM, int TN, int WM>
static void launch_bg(int act, int outbf,
                      const ushort_t* A, int lda, long sA1, long sA2,
                      const ushort_t* B, int ldb, long sB1, long sB2,
                      void* C, int ldc, long sC1, long sC2,
                      const float* bias, int M, int N, int K, float alpha,
                      int batchH, int Z, int taps, long tapA, long tapB,
                      const ushort_t* zbuf, hipStream_t st) {
    dim3 grid((N + TN - 1) / TN, (M + TM - 1) / TM, Z), blk(256);
#define BG(A_, O_) bgemm_k<TM, TN, WM, A_, O_><<<grid, blk, 0, st>>>(A, lda, sA1, sA2, B, ldb, sB1, sB2, C, ldc, sC1, sC2, bias, M, N, K, alpha, batchH, taps, tapA, tapB, zbuf)
    if (act) { if (outbf) BG(1, 1); else BG(1, 0); }
    else     { if (outbf) BG(0, 1); else BG(0, 0); }
#undef BG
}

// ================= fused attention (QK^T -> softmax -> PV) ==================
template<int CHECKQ>
__global__ __launch_bounds__(256) void fattn_k(
    const ushort_t* __restrict__ Q, int ldq, long sQb, long sQc,
    const ushort_t* __restrict__ K, int ldk, long sKb,
    const ushort_t* __restrict__ VT, long sVb,
    ushort_t* __restrict__ O, int ldo, long sOb, long sOc,
    int nc, int Mtot, const ushort_t* __restrict__ zbuf)
{
    __shared__ __align__(16) ushort_t Qs[128 * 64];
    __shared__ __align__(16) ushort_t Ks[128 * 64];
    __shared__ __align__(16) ushort_t Vs[64 * 128];
    __shared__ __align__(16) ushort_t Ps[128 * 128];
    int z = blockIdx.x;
    int c = z % nc, rr_ = z / nc;
    int h = rr_ % HH, b = rr_ / HH;
    int mQ = Mtot - c * 128;
    const ushort_t* Qb = Q + (long)b * sQb + (long)c * sQc + h * 64;
    const ushort_t* Kb = K + (long)b * sKb + h * 64;
    const ushort_t* Vb = VT + (long)b * sVb + (long)h * 64 * 128;
    ushort_t* Ob = O + (long)b * sOb + (long)c * sOc + h * 64;

    int tid = threadIdx.x, wid = tid >> 6, lane = tid & 63;
    int lr = lane & 15, lg = lane >> 4;

    {
        int rsub = lane >> 3, csub = lane & 7;
        #pragma unroll
        for (int i = 0; i < 4; i++) {
            int row = wid * 32 + i * 8 + rsub;
            int cc = (csub ^ rsub) * 8;
            const ushort_t* qs = (!CHECKQ || row < mQ) ? (Qb + (long)row * ldq + cc) : zbuf;
            gld16(qs, &Qs[(wid * 32 + i * 8) * 64]);
            gld16(Kb + (long)row * ldk + cc, &Ks[(wid * 32 + i * 8) * 64]);
        }
        int d4 = lane >> 4, c16 = lane & 15;
        #pragma unroll
        for (int i = 0; i < 4; i++) {
            int d = wid * 16 + i * 4 + d4;
            int cc = (c16 ^ (d & 7)) * 8;
            gld16(Vb + (long)d * 128 + cc, &Vs[(wid * 16 + i * 4) * 128]);
        }
    }
    __syncthreads();

    floatx4 acc[2][8];
    #pragma unroll
    for (int i = 0; i < 2; i++)
        #pragma unroll
        for (int j = 0; j < 8; j++)
            acc[i][j] = (floatx4){0.f, 0.f, 0.f, 0.f};
    const char* Qc = (const char*)Qs;
    const char* Kc = (const char*)Ks;
    #pragma unroll
    for (int kk = 0; kk < 2; kk++) {
        bhalf8 a_[2], b_[8];
        #pragma unroll
        for (int i = 0; i < 2; i++) {
            int r = wid * 32 + i * 16 + lr;
            a_[i] = *(const bhalf8*)(Qc + (r << 7) + ((((kk << 2) + lg) ^ (r & 7)) << 4));
        }
        #pragma unroll
        for (int j = 0; j < 8; j++) {
            int r = j * 16 + lr;
            b_[j] = *(const bhalf8*)(Kc + (r << 7) + ((((kk << 2) + lg) ^ (r & 7)) << 4));
        }
        #pragma unroll
        for (int i = 0; i < 2; i++)
            #pragma unroll
            for (int j = 0; j < 8; j++)
                acc[i][j] = __builtin_amdgcn_mfma_f32_16x16x32_bf16(
                    a_[i], b_[j], acc[i][j], 0, 0, 0);
    }

    #pragma unroll
    for (int i = 0; i < 2; i++) {
        #pragma unroll
        for (int r = 0; r < 4; r++) {
            int row = wid * 32 + i * 16 + lg * 4 + r;
            float v[8], m = -1e30f;
            #pragma unroll
            for (int j = 0; j < 8; j++) { v[j] = acc[i][j][r] * 0.125f; m = fmaxf(m, v[j]); }
            #pragma unroll
            for (int o = 8; o > 0; o >>= 1) m = fmaxf(m, __shfl_xor(m, o, 64));
            float s = 0.f;
            #pragma unroll
            for (int j = 0; j < 8; j++) { v[j] = expf(v[j] - m); s += v[j]; }
            #pragma unroll
            for (int o = 8; o > 0; o >>= 1) s += __shfl_xor(s, o, 64);
            float inv = 1.f / s;
            #pragma unroll
            for (int j = 0; j < 8; j++) {
                int col = j * 16 + lr;
                int byte = (row << 8) + ((((col >> 3) ^ (row & 7)) << 4)) + ((col & 7) << 1);
                *(ushort_t*)((char*)Ps + byte) = f2b(v[j] * inv);
            }
        }
    }
    __syncthreads();

    floatx4 acc2[2][4];
    #pragma unroll
    for (int i = 0; i < 2; i++)
        #pragma unroll
        for (int j = 0; j < 4; j++)
            acc2[i][j] = (floatx4){0.f, 0.f, 0.f, 0.f};
    const char* Pc = (const char*)Ps;
    const char* Vc = (const char*)Vs;
    #pragma unroll
    for (int kk = 0; kk < 4; kk++) {
        bhalf8 a_[2], b_[4];
        #pragma unroll
        for (int i = 0; i < 2; i++) {
            int r = wid * 32 + i * 16 + lr;
            a_[i] = *(const bhalf8*)(Pc + (r << 8) + ((((kk << 2) + lg) ^ (r & 7)) << 4));
        }
        #pragma unroll
        for (int j = 0; j < 4; j++) {
            int d = j * 16 + lr;
            b_[j] = *(const bhalf8*)(Vc + (d << 8) + ((((kk << 2) + lg) ^ (d & 7)) << 4));
        }
        #pragma unroll
        for (int i = 0; i < 2; i++)
            #pragma unroll
            for (int j = 0; j < 4; j++)
                acc2[i][j] = __builtin_amdgcn_mfma_f32_16x16x32_bf16(
                    a_[i], b_[j], acc2[i][j], 0, 0, 0);
    }
    #pragma unroll
    for (int i = 0; i < 2; i++) {
        #pragma unroll
        for (int r = 0; r < 4; r++) {
            int q = wid * 32 + i * 16 + lg * 4 + r;
            if (CHECKQ && q >= mQ) continue;
            #pragma unroll
            for (int j = 0; j < 4; j++) {
                int d = j * 16 + lr;
                Ob[(long)q * ldo + d] = f2b(acc2[i][j][r]);
            }
        }
    }
}

// ================= fp32 tiled GEMM (logits only) =================
template<int TRANSB>
__global__ __launch_bounds__(256) void gemm_k(
    const float* __restrict__ A, int lda,
    const float* __restrict__ B, int ldb,
    float* __restrict__ C, int ldc,
    int M, int N, int K)
{
    __shared__ float As[16][68];
    __shared__ float Bs[16][68];
    int m0 = blockIdx.y * 64, n0 = blockIdx.x * 64;
    int tid = threadIdx.x;
    int tr = tid / 16, tc = tid % 16;
    float acc[4][4] = {};
    for (int k0 = 0; k0 < K; k0 += 16) {
        {
            int ar = tid / 4;
            int ac = (tid % 4) * 4;
            int gm = m0 + ar;
            #pragma unroll
            for (int i = 0; i < 4; i++) {
                int gk = k0 + ac + i;
                As[ac + i][ar] = (gm < M && gk < K) ? A[(long)gm * lda + gk] : 0.f;
            }
        }
        {
            int bn = tid / 4;
            int bk = (tid % 4) * 4;
            int gn = n0 + bn;
            #pragma unroll
            for (int i = 0; i < 4; i++) {
                int gk = k0 + bk + i;
                Bs[bk + i][bn] = (gn < N && gk < K) ? B[(long)gn * ldb + gk] : 0.f;
            }
        }
        __syncthreads();
        #pragma unroll
        for (int kk = 0; kk < 16; kk++) {
            float a[4], b[4];
            #pragma unroll
            for (int i = 0; i < 4; i++) a[i] = As[kk][tr * 4 + i];
            #pragma unroll
            for (int i = 0; i < 4; i++) b[i] = Bs[kk][tc * 4 + i];
            #pragma unroll
            for (int i = 0; i < 4; i++)
                #pragma unroll
                for (int j = 0; j < 4; j++)
                    acc[i][j] += a[i] * b[j];
        }
        __syncthreads();
    }
    #pragma unroll
    for (int i = 0; i < 4; i++) {
        int gm = m0 + tr * 4 + i;
        if (gm >= M) continue;
        #pragma unroll
        for (int j = 0; j < 4; j++) {
            int gn = n0 + tc * 4 + j;
            if (gn >= N) continue;
            C[(long)gm * ldc + gn] = acc[i][j];
        }
    }
}

// ================= conversions =================
__global__ void f2b_k(const float* __restrict__ in, ushort_t* __restrict__ out, long n) {
    long stride = (long)gridDim.x * blockDim.x * 8;
    for (long i = ((long)blockIdx.x * blockDim.x + threadIdx.x) * 8; i < n; i += stride) {
        float4 a = *(const float4*)(in + i);
        float4 b = *(const float4*)(in + i + 4);
        uint4 o;
        o.x = (unsigned)f2b(a.x) | ((unsigned)f2b(a.y) << 16);
        o.y = (unsigned)f2b(a.z) | ((unsigned)f2b(a.w) << 16);
        o.z = (unsigned)f2b(b.x) | ((unsigned)f2b(b.y) << 16);
        o.w = (unsigned)f2b(b.z) | ((unsigned)f2b(b.w) << 16);
        *(uint4*)(out + i) = o;
    }
}
__global__ void add_f2b_k(const float* __restrict__ a, const float* __restrict__ b,
                          ushort_t* __restrict__ out, long n) {
    long stride = (long)gridDim.x * blockDim.x * 8;
    for (long i = ((long)blockIdx.x * blockDim.x + threadIdx.x) * 8; i < n; i += stride) {
        float4 x = *(const float4*)(a + i);
        float4 y = *(const float4*)(b + i);
        float4 x2 = *(const float4*)(a + i + 4);
        float4 y2 = *(const float4*)(b + i + 4);
        uint4 o;
        o.x = (unsigned)f2b(x.x + y.x) | ((unsigned)f2b(x.y + y.y) << 16);
        o.y = (unsigned)f2b(x.z + y.z) | ((unsigned)f2b(x.w + y.w) << 16);
        o.z = (unsigned)f2b(x2.x + y2.x) | ((unsigned)f2b(x2.y + y2.y) << 16);
        o.w = (unsigned)f2b(x2.z + y2.z) | ((unsigned)f2b(x2.w + y2.w) << 16);
        *(uint4*)(out + i) = o;
    }
}
// transpose+convert fp32 (R x C) -> bf16 (C x R), batched over z
__global__ void f2b_t_k(const float* __restrict__ in, ushort_t* __restrict__ out,
                        int R, int C, long inStride, long outStride) {
    __shared__ float tile[32][33];
    int z = blockIdx.z;
    in += (long)z * inStride;
    out += (long)z * outStride;
    int c0 = blockIdx.x * 32, r0 = blockIdx.y * 32;
    int tx = threadIdx.x, ty = threadIdx.y;
    #pragma unroll
    for (int i = 0; i < 32; i += 8) {
        int r = r0 + ty + i, c = c0 + tx;
        tile[ty + i][tx] = (r < R && c < C) ? in[(long)r * C + c] : 0.f;
    }
    __syncthreads();
    #pragma unroll
    for (int i = 0; i < 32; i += 8) {
        int c = c0 + ty + i, r = r0 + tx;
        if (c < C && r < R) out[(long)c * R + r] = f2b(tile[tx][ty + i]);
    }
}
// bf16 transpose: in (R x C, ldin) -> out (C x R), batched over z
__global__ void t_bf_k(const ushort_t* __restrict__ in, ushort_t* __restrict__ out,
                       int R, int C, int ldin, long inStride, long outStride) {
    __shared__ ushort_t tile[32][33];
    int z = blockIdx.z;
    in += (long)z * inStride;
    out += (long)z * outStride;
    int c0 = blockIdx.x * 32, r0 = blockIdx.y * 32;
    int tx = threadIdx.x, ty = threadIdx.y;
    #pragma unroll
    for (int i = 0; i < 32; i += 8) {
        int r = r0 + ty + i, c = c0 + tx;
        if (r < R && c < C) tile[ty + i][tx] = in[(long)r * ldin + c];
    }
    __syncthreads();
    #pragma unroll
    for (int i = 0; i < 32; i += 8) {
        int c = c0 + ty + i, r = r0 + tx;
        if (c < C && r < R) out[(long)c * R + r] = tile[tx][ty + i];
    }
}
__global__ void cat3all_k(float* __restrict__ dst, const float* __restrict__ a,
                          const float* __restrict__ b, const float* __restrict__ c) {
    int i = blockIdx.x * blockDim.x + threadIdx.x;
    if (i >= LL * 1536) return;
    int l = i / 1536, j = i % 1536;
    float v = (j < 512) ? a[l * 512 + j]
            : (j < 1024) ? b[l * 512 + j - 512] : c[l * 512 + j - 1024];
    dst[i] = v;
}

// ---------------- elementwise ----------------
__global__ void addpos_bf_k(const float* __restrict__ a, const float* __restrict__ pos,
                            float* __restrict__ o, ushort_t* __restrict__ obf,
                            long n, long pmod) {
    for (long i = blockIdx.x * (long)blockDim.x + threadIdx.x; i < n;
         i += (long)gridDim.x * blockDim.x) {
        float v = a[i] + pos[i % pmod];
        o[i] = v;
        obf[i] = f2b(v);
    }
}
__global__ void zero_k(float* __restrict__ p, long n) {
    for (long i = blockIdx.x * (long)blockDim.x + threadIdx.x; i < n;
         i += (long)gridDim.x * blockDim.x)
        p[i] = 0.f;
}
__global__ void sentinel_k(float* p) { p[0] = 1e9f; }
// zero pad rows r=0 and r=129 of a (B,130,CO) channel-last buffer
__global__ void padzero_k(ushort_t* __restrict__ h, int CO) {
    int b = blockIdx.x;
    for (int i = threadIdx.x; i < CO; i += blockDim.x) {
        h[(long)b * 130 * CO + i] = 0;
        h[((long)b * 130 + 129) * CO + i] = 0;
    }
}

// ---------------- residual + layernorm ----------------
__global__ __launch_bounds__(256) void ln_res_k(float* __restrict__ x,
                                                const float* __restrict__ z,
                                                ushort_t* __restrict__ xbf,
                                                const float* __restrict__ g,
                                                const float* __restrict__ b) {
    long row = blockIdx.x;
    float* px = x + row * DD;
    const float* pz = z + row * DD;
    ushort_t* pb = xbf + row * DD;
    int t = threadIdx.x;
    float v0 = px[t] + pz[t];
    float v1 = px[t + 256] + pz[t + 256];
    float s = v0 + v1, sq = v0 * v0 + v1 * v1;
    for (int o = 32; o > 0; o >>= 1) {
        s += __shfl_xor(s, o, 64);
        sq += __shfl_xor(sq, o, 64);
    }
    __shared__ float ss[4], sqq[4];
    int wave = t >> 6, lane = t & 63;
    if (lane == 0) { ss[wave] = s; sqq[wave] = sq; }
    __syncthreads();
    s = ss[0] + ss[1] + ss[2] + ss[3];
    sq = sqq[0] + sqq[1] + sqq[2] + sqq[3];
    float mean = s * (1.f / DD);
    float var = sq * (1.f / DD) - mean * mean;
    float rstd = 1.f / sqrtf(var + 1e-5f);
    float o0 = (v0 - mean) * rstd * g[t] + b[t];
    float o1 = (v1 - mean) * rstd * g[t + 256] + b[t + 256];
    px[t] = o0;
    px[t + 256] = o1;
    pb[t] = f2b(o0);
    pb[t + 256] = f2b(o1);
}

// ---------------- conv helpers ----------------
__global__ void pad_copy_bf_k(const float* __restrict__ fp, ushort_t* __restrict__ fpp) {
    long total = (long)BB * TT * NW;
    for (long i = blockIdx.x * (long)blockDim.x + threadIdx.x; i < total;
         i += (long)gridDim.x * blockDim.x) {
        long ci = i % NW;
        long r = i / NW;
        long t = r % TT;
        long b = r / TT;
        fpp[(b * 130 + t + 1) * NW + ci] = f2b(fp[i]);
    }
}
__global__ void repack_bf_k(const float* __restrict__ w, ushort_t* __restrict__ wk,
                            int CO, int CI) {
    long total = (long)CO * CI * 3;
    for (long i = blockIdx.x * (long)blockDim.x + threadIdx.x; i < total;
         i += (long)gridDim.x * blockDim.x) {
        long kt = i % 3;
        long r = i / 3;
        long ci = r % CI;
        long co = r / CI;
        wk[kt * (long)CO * CI + co * CI + ci] = f2b(w[i]);
    }
}
__global__ __launch_bounds__(128) void conv5_bf_k(const ushort_t* __restrict__ h4,
                                                  const float* __restrict__ w,
                                                  const float* __restrict__ bias,
                                                  float* __restrict__ out) {
    int b = blockIdx.x, t = threadIdx.x;
    __shared__ float wsm[384];
    wsm[t] = w[t];
    wsm[t + 128] = w[t + 128];
    wsm[t + 256] = w[t + 256];
    __syncthreads();
    const ushort_t* hb = h4 + (long)b * 130 * 128;
    float acc = bias[0];
    for (int ci = 0; ci < 128; ci++) {
        float w0 = wsm[ci * 3], w1 = wsm[ci * 3 + 1], w2 = wsm[ci * 3 + 2];
        acc += w0 * b2f(hb[(t + 0) * 128 + ci]) + w1 * b2f(hb[(t + 1) * 128 + ci]) +
               w2 * b2f(hb[(t + 2) * 128 + ci]);
    }
    out[b * TT + t] = 1.f / (1.f + expf(-acc));
}

// ---------------- masked segment softmax pooling ----------------
__global__ __launch_bounds__(128) void seg_pool_k(const float* __restrict__ weights,
                                                  const int* __restrict__ steds,
                                                  const float* __restrict__ vid,
                                                  float* __restrict__ segf) {
    int b = blockIdx.y, sidx = blockIdx.x;
    int st = steds[(b * SS + sidx) * 2];
    int ed = steds[(b * SS + sidx) * 2 + 1];
    int t = threadIdx.x;
    float w = (t >= st && t <= ed) ? weights[b * TT + t] : -1e30f;
    __shared__ float red[2];
    __shared__ float aw[TT];
    int wave = t >> 6, lane = t & 63;
    float m = w;
    for (int o = 32; o > 0; o >>= 1) m = fmaxf(m, __shfl_xor(m, o, 64));
    if (lane == 0) red[wave] = m;
    __syncthreads();
    m = fmaxf(red[0], red[1]);
    float e = expf(w - m);
    float sum = e;
    for (int o = 32; o > 0; o >>= 1) sum += __shfl_xor(sum, o, 64);
    __syncthreads();
    if (lane == 0) red[wave] = sum;
    __syncthreads();
    sum = red[0] + red[1];
    aw[t] = e / sum;
    __syncthreads();
    #pragma unroll
    for (int i = 0; i < 4; i++) {
        int d = t + i * 128;
        float acc = 0.f;
        for (int tt = 0; tt < TT; tt++)
            acc += aw[tt] * vid[((long)b * TT + tt) * DD + d];
        segf[((long)b * SS + sidx) * DD + d] = acc;
    }
}

extern "C" void kernel_launch(void* const* d_in, const int* in_sizes, int n_in,
                              void* d_out, int out_size, void* d_ws, size_t ws_size,
                              hipStream_t stream) {
    const float* vid = (const float*)d_in[0];
    const float* actn_feats = (const float*)d_in[2];
    const float* actn_concepts = (const float*)d_in[3];
    const float* pos = (const float*)d_in[4];
    const float* Wq = (const float*)d_in[5];
    const float* bq = (const float*)d_in[6];
    const float* Wk = (const float*)d_in[7];
    const float* bk = (const float*)d_in[8];
    const float* Wv = (const float*)d_in[9];
    const float* bv = (const float*)d_in[10];
    const float* Wo = (const float*)d_in[11];
    const float* bo = (const float*)d_in[12];
    const float* W1 = (const float*)d_in[13];
    const float* b1 = (const float*)d_in[14];
    const float* W2 = (const float*)d_in[15];
    const float* b2 = (const float*)d_in[16];
    const float* g1 = (const float*)d_in[17];
    const float* bb1 = (const float*)d_in[18];
    const float* g2 = (const float*)d_in[19];
    const float* bb2 = (const float*)d_in[20];
    const float* pqW = (const float*)d_in[21];
    const float* pqb = (const float*)d_in[22];
    const float* pkW = (const float*)d_in[23];
    const float* pkb = (const float*)d_in[24];
    const float* pvW = (const float*)d_in[25];
    const float* pvb = (const float*)d_in[26];
    const float* c1w = (const float*)d_in[27];
    const float* c1b = (const float*)d_in[28];
    const float* c2w = (const float*)d_in[29];
    const float* c2b = (const float*)d_in[30];
    const float* c3w = (const float*)d_in[31];
    const float* c3b = (const float*)d_in[32];
    const float* c4w = (const float*)d_in[33];
    const float* c4b = (const float*)d_in[34];
    const float* c5w = (const float*)d_in[35];
    const float* c5b = (const float*)d_in[36];
    const int* steds = (const int*)d_in[37];

    float* out = (float*)d_out;
    float* fc_out = out;            // 32*128
    float* al_out = out + 4096;     // 32*8*200
    float* fp_out = out + 55296;    // 32*128*2000

    float* ws = (float*)d_ws;
    const long NEED = 25165824;  // floats (96 MiB)
    if (ws_size < (size_t)NEED * 4) {
        sentinel_k<<<1, 1, 0, stream>>>(fc_out);
        return;
    }

    // ---- arena (float-unit offsets) ----
    // phase A:
    const long A_XBF   = 0;          // x bf16 (1,048,576)
    const long A_QKVBF = 1048576;    // qkv bf16 (3,145,728) -> 4,194,304
    const long A_VT    = 4194304;    // vT bf16 (1,048,576) -> 5,242,880
    const long A_FFH   = 7340032;    // ffh bf16 (4,194,304) -> 11,534,336
    const long A_AOBF  = 11534336;   // attn out bf16 (1,048,576) -> 12,582,912
    const long A_QB    = 12582912;   // fp32 scratch (2,097,152) -> 14,680,064
    const long A_QKVT  = 14680064;   // -> 16,252,928
    const long A_WOT   = 16252928;   // -> 16,777,216
    const long A_W1T   = 16777216;   // -> 18,874,368
    const long A_W2T   = 18874368;   // -> 20,971,520
    const long A_QKVB  = 20971520;   // -> 20,977,664
    const long XB      = 21000192;   // x fp32 -> 23,097,344
    // phase B:
    const long B_UPD   = 0;          // upd bf16 full (16,384,000) -> 16,384,000
    const long B_VPRBF = 16384000;   // vproj bf16 -> 17,432,576
    const long B_PW    = 17432576;   // -> 17,825,792
    const long B_ACBF  = 17825792;   // -> 18,337,792
    const long B_QPBF  = 18337792;   // -> 18,849,792
    const long B_KPBF  = 18849792;   // -> 19,898,368
    const long B_VP    = 19898368;   // Vp fp32 -> 21,995,520
    const long B_VPT   = 21995520;   // VpT bf16 -> 23,044,096
    // phase C:
    const long C_FPP   = 0;
    const long C_WK1   = 4160000;
    const long C_WK2   = 7232000;
    const long C_WK3   = 8018432;
    const long C_WK4   = 8215040;
    const long C_H1    = 8264192;
    const long C_H2    = 10394112;
    const long C_H3    = 11459072;
    const long C_H4    = 11991552;
    const long C_SEGF  = 12257792;   // -> 12,388,864
    const long ZPAD    = 25165760;   // zbuf (64 floats)

    float* xb = ws + XB;
    const ushort_t* zbuf = (const ushort_t*)(ws + ZPAD);
    const long nBTD = (long)BB * TT * DD;

    zero_k<<<1, 64, 0, stream>>>(ws + ZPAD, 64);

    ushort_t* xbf = (ushort_t*)(ws + A_XBF);
    addpos_bf_k<<<2048, 256, 0, stream>>>(vid, pos, xb, xbf, nBTD, (long)TT * DD);

    // ---- all-layer weight prep ----
    ushort_t* qkvT = (ushort_t*)(ws + A_QKVT);
    ushort_t* WoT  = (ushort_t*)(ws + A_WOT);
    ushort_t* W1T  = (ushort_t*)(ws + A_W1T);
    ushort_t* W2T  = (ushort_t*)(ws + A_W2T);
    float*    qkvb = ws + A_QKVB;
    dim3 tblk(32, 8);
    f2b_t_k<<<dim3(16, 16, LL), tblk, 0, stream>>>(Wq, qkvT, DD, DD, (long)DD * DD, 786432);
    f2b_t_k<<<dim3(16, 16, LL), tblk, 0, stream>>>(Wk, qkvT + 262144, DD, DD, (long)DD * DD, 786432);
    f2b_t_k<<<dim3(16, 16, LL), tblk, 0, stream>>>(Wv, qkvT + 524288, DD, DD, (long)DD * DD, 786432);
    f2b_t_k<<<dim3(16, 16, LL), tblk, 0, stream>>>(Wo, WoT, DD, DD, (long)DD * DD, 262144);
    f2b_t_k<<<dim3(64, 16, LL), tblk, 0, stream>>>(W1, W1T, DD, FF, (long)DD * FF, 1048576);
    f2b_t_k<<<dim3(16, 64, LL), tblk, 0, stream>>>(W2, W2T, FF, DD, (long)FF * DD, 1048576);
    cat3all_k<<<(LL * 1536 + 255) / 256, 256, 0, stream>>>(qkvb, bq, bk, bv);

    // ================= phase A: transformer =================
    ushort_t* qkvbf = (ushort_t*)(ws + A_QKVBF);
    ushort_t* vTb   = (ushort_t*)(ws + A_VT);
    ushort_t* ffhbf = (ushort_t*)(ws + A_FFH);
    ushort_t* aobf  = (ushort_t*)(ws + A_AOBF);
    float*    qb    = ws + A_QB;

    for (int l = 0; l < LL; l++) {
        // QKV: 128x128 tile (384 blocks, compute-dense)
        launch_bg<128, 128, 2>(0, 1, xbf, DD, 0, 0, qkvT + (long)l * 786432, DD, 0, 0,
                               qkvbf, 1536, 0, 0, qkvb + (long)l * 1536,
                               BB * TT, 1536, DD, 1.f, 1, 1, 1, 0, 0, zbuf, stream);
        t_bf_k<<<dim3(16, 4, BB), tblk, 0, stream>>>(qkvbf + 1024, vTb, TT, DD, 1536,
                                                     (long)TT * 1536, (long)DD * TT);
        fattn_k<0><<<BB * HH, 256, 0, stream>>>(
            qkvbf, 1536, (long)TT * 1536, 0,
            qkvbf + 512, 1536, (long)TT * 1536,
            vTb, (long)DD * TT,
            aobf, DD, (long)TT * DD, 0, 1, TT, zbuf);
        // Wo: 64x64 (512 blocks, was 128 @ 0.5/CU)
        launch_bg<64, 64, 2>(0, 0, aobf, DD, 0, 0, WoT + (long)l * 262144, DD, 0, 0,
                             qb, DD, 0, 0, bo + (long)l * DD,
                             BB * TT, DD, DD, 1.f, 1, 1, 1, 0, 0, zbuf, stream);
        ln_res_k<<<BB * TT, 256, 0, stream>>>(xb, qb, xbf, g1 + (long)l * DD, bb1 + (long)l * DD);
        // FF1: 128x128 (512 blocks)
        launch_bg<128, 128, 2>(1, 1, xbf, DD, 0, 0, W1T + (long)l * 1048576, DD, 0, 0,
                               ffhbf, FF, 0, 0, b1 + (long)l * FF,
                               BB * TT, FF, DD, 1.f, 1, 1, 1, 0, 0, zbuf, stream);
        // FF2: 64x64 (512 blocks, was 128 @ 0.5/CU)
        launch_bg<64, 64, 2>(0, 0, ffhbf, FF, 0, 0, W2T + (long)l * 1048576, FF, 0, 0,
                             qb, DD, 0, 0, b2 + (long)l * DD,
                             BB * TT, DD, FF, 1.f, 1, 1, 1, 0, 0, zbuf, stream);
        ln_res_k<<<BB * TT, 256, 0, stream>>>(xb, qb, xbf, g2 + (long)l * DD, bb2 + (long)l * DD);
    }

    // ================= phase B: cross-attn + feats_proj =================
    ushort_t* updbf = (ushort_t*)(ws + B_UPD);
    ushort_t* vprbf = (ushort_t*)(ws + B_VPRBF);
    ushort_t* pqT   = (ushort_t*)(ws + B_PW);
    ushort_t* pkT   = (ushort_t*)(ws + B_PW + 131072);
    ushort_t* pvT   = (ushort_t*)(ws + B_PW + 262144);
    ushort_t* acbf  = (ushort_t*)(ws + B_ACBF);
    ushort_t* Qpbf  = (ushort_t*)(ws + B_QPBF);
    ushort_t* Kpbf  = (ushort_t*)(ws + B_KPBF);
    float*    Vp    = ws + B_VP;
    ushort_t* VpT   = (ushort_t*)(ws + B_VPT);

    add_f2b_k<<<1024, 256, 0, stream>>>(vid, xb, vprbf, nBTD);   // xb dead after
    f2b_t_k<<<dim3(16, 16, 1), tblk, 0, stream>>>(pqW, pqT, DD, DD, 0, 0);
    f2b_t_k<<<dim3(16, 16, 1), tblk, 0, stream>>>(pkW, pkT, DD, DD, 0, 0);
    f2b_t_k<<<dim3(16, 16, 1), tblk, 0, stream>>>(pvW, pvT, DD, DD, 0, 0);
    f2b_k<<<512, 256, 0, stream>>>(actn_concepts, acbf, (long)NW * DD);

    launch_bg<64, 64, 2>(0, 1, acbf, DD, 0, 0, pqT, DD, 0, 0, Qpbf, DD, 0, 0,
                         pqb, NW, DD, DD, 1.f, 1, 1, 1, 0, 0, zbuf, stream);
    launch_bg<64, 64, 2>(0, 1, vprbf, DD, 0, 0, pkT, DD, 0, 0, Kpbf, DD, 0, 0,
                         pkb, BB * TT, DD, DD, 1.f, 1, 1, 1, 0, 0, zbuf, stream);
    launch_bg<64, 64, 2>(0, 0, vprbf, DD, 0, 0, pvT, DD, 0, 0, Vp, DD, 0, 0,
                         pvb, BB * TT, DD, DD, 1.f, 1, 1, 1, 0, 0, zbuf, stream);
    f2b_t_k<<<dim3(16, 4, BB), tblk, 0, stream>>>(Vp, VpT, TT, DD, (long)TT * DD, (long)TT * DD);

    // fused cross-attention: one launch, 16 concept-chunks of 128
    fattn_k<1><<<BB * HH * 16, 256, 0, stream>>>(
        Qpbf, DD, 0, (long)128 * DD,
        Kpbf, DD, (long)TT * DD,
        VpT, (long)DD * TT,
        updbf, DD, (long)NW * DD, (long)128 * DD, 16, NW, zbuf);

    // feats_proj: fp[b,t,n] = vproj[b,t,:] . upd[b,n,:]  (128x128, 512 blocks)
    launch_bg<128, 128, 2>(0, 0, vprbf, DD, (long)TT * DD, 0,
                           updbf, DD, (long)NW * DD, 0,
                           fp_out, NW, (long)TT * NW, 0,
                           nullptr, TT, NW, DD, 1.f, 1, BB, 1, 0, 0, zbuf, stream);

    // ================= phase C: conv tower (merged-M, taps as row shifts) ===
    ushort_t* fpp = (ushort_t*)(ws + C_FPP);
    ushort_t* wk1 = (ushort_t*)(ws + C_WK1);
    ushort_t* wk2 = (ushort_t*)(ws + C_WK2);
    ushort_t* wk3 = (ushort_t*)(ws + C_WK3);
    ushort_t* wk4 = (ushort_t*)(ws + C_WK4);
    ushort_t* h1  = (ushort_t*)(ws + C_H1);
    ushort_t* h2  = (ushort_t*)(ws + C_H2);
    ushort_t* h3  = (ushort_t*)(ws + C_H3);
    ushort_t* h4  = (ushort_t*)(ws + C_H4);

    repack_bf_k<<<1024, 256, 0, stream>>>(c1w, wk1, 1024, NW);
    repack_bf_k<<<512, 256, 0, stream>>>(c2w, wk2, 512, 1024);
    repack_bf_k<<<256, 256, 0, stream>>>(c3w, wk3, 256, 512);
    repack_bf_k<<<128, 256, 0, stream>>>(c4w, wk4, 128, 256);
    padzero_k<<<BB, 256, 0, stream>>>(fpp, NW);
    pad_copy_bf_k<<<2048, 256, 0, stream>>>(fp_out, fpp);

    const int MROWS = BB * 130 - 2;  // 4158: out row gm -> padded row gm+1
    // conv1: 128x64 tile -> 528 blocks (was 264)
    launch_bg<128, 64, 4>(1, 1, fpp, NW, 0, 0, wk1, NW, 0, 0,
                          h1 + 1024, 1024, 0, 0, c1b,
                          MROWS, 1024, NW, 1.f, 1, 1, 3, NW, (long)1024 * NW, zbuf, stream);
    padzero_k<<<BB, 256, 0, stream>>>(h1, 1024);
    // conv2: 64x64 -> 520 blocks (was 132)
    launch_bg<64, 64, 2>(1, 1, h1, 1024, 0, 0, wk2, 1024, 0, 0,
                         h2 + 512, 512, 0, 0, c2b,
                         MROWS, 512, 1024, 1.f, 1, 1, 3, 1024, (long)512 * 1024, zbuf, stream);
    padzero_k<<<BB, 256, 0, stream>>>(h2, 512);
    // conv3: 64x64 -> 260 blocks (was 66)
    launch_bg<64, 64, 2>(1, 1, h2, 512, 0, 0, wk3, 512, 0, 0,
                         h3 + 256, 256, 0, 0, c3b,
                         MROWS, 256, 512, 1.f, 1, 1, 3, 512, (long)256 * 512, zbuf, stream);
    padzero_k<<<BB, 256, 0, stream>>>(h3, 256);
    // conv4: 64x64 -> 130 blocks (was 33)
    launch_bg<64, 64, 2>(1, 1, h3, 256, 0, 0, wk4, 256, 0, 0,
                         h4 + 128, 128, 0, 0, c4b,
                         MROWS, 128, 256, 1.f, 1, 1, 3, 256, (long)128 * 256, zbuf, stream);
    padzero_k<<<BB, 256, 0, stream>>>(h4, 128);
    conv5_bf_k<<<BB, 128, 0, stream>>>(h4, c5w, c5b, fc_out);

    // ================= segment pooling + logits (fp32) =================
    float* segf = ws + C_SEGF;
    seg_pool_k<<<dim3(SS, BB), 128, 0, stream>>>(fc_out, steds, vid, segf);
    gemm_k<1><<<dim3((NCC + 63) / 64, (BB * SS + 63) / 64, 1), 256, 0, stream>>>(
        segf, DD, actn_feats, DD, al_out, NCC, BB * SS, NCC, DD);
}